// Round 1
// baseline (272.204 us; speedup 1.0000x reference)
//
#include <hip/hip_runtime.h>
#include <math.h>

#define EPS32 1.1920928955078125e-07f
#define NSP 32768   // 2*128*128 spatial positions

// ---------------- ws layout (float/int units) ----------------
// 0    : cxi[128] (int)      128 : cyi[128]       256 : czi[128]
// 384  : rx[128]             512 : rz[128]        640 : valid[128]
// 768  : i2sx[128] (float)   896 : i2sy[128]      1024: i2sz[128]
// 1152 : partial[128]        1280: scale[1]
// 2048 : hmv[32768]          65536: pooled[64*32768]

__device__ __forceinline__ float gauss_radius(float h, float w) {
#pragma clang fp contract(off)
    const float mo = 0.1f;
    float b1 = h + w;
    float c1 = w * h * (1.0f - mo) / (1.0f + mo);
    float r1 = (b1 + sqrtf(fmaxf(b1 * b1 - 4.0f * c1, 0.0f))) / 2.0f;
    float b2 = 2.0f * (h + w);
    float c2 = (1.0f - mo) * w * h;
    float r2 = (b2 + sqrtf(fmaxf(b2 * b2 - 16.0f * c2, 0.0f))) / 2.0f;
    float b3 = -2.0f * mo * (h + w);
    float c3 = (mo - 1.0f) * w * h;
    float r3 = (b3 + sqrtf(fmaxf(b3 * b3 - 16.0f * mo * c3, 0.0f))) / 2.0f;
    return fminf(fminf(r1, r2), r3);
}

__global__ void k_params(const float* __restrict__ boxes, int N,
                         int* wsI, float* wsF) {
#pragma clang fp contract(off)
    int b = threadIdx.x;
    if (b >= N) return;
    float x = boxes[b * 9 + 0];
    float y = boxes[b * 9 + 1];
    float z = boxes[b * 9 + 2];
    float wf = boxes[b * 9 + 3] / 0.1f / 8.0f;
    float lf = boxes[b * 9 + 4] / 0.1f / 8.0f;
    float hf = boxes[b * 9 + 5] / 0.2f / 8.0f;
    float r_xy = gauss_radius(lf, wf);
    float r_z  = fmaxf(gauss_radius(lf, hf), gauss_radius(wf, hf));
    int rx = max(2, (int)truncf(r_xy / 0.4f));
    int rz = max(2, (int)truncf(r_z / 1.0f));
    float cx = (x + 51.2f) / 0.4f;
    float cy = (y + 51.2f) / 0.4f;
    float cz = (z + 5.0f) / 1.0f;
    int cxi = (int)cx, cyi = (int)cy, czi = (int)cz;
    int valid = (wf > 0.0f) && (lf > 0.0f) &&
                cxi >= 0 && cxi < 128 && cyi >= 0 && cyi < 128 &&
                czi >= 0 && czi <= 1;
    float sx = (2.0f * (float)rx + 1.0f) / 6.0f;
    float sz = (2.0f * (float)rz + 1.0f) / 6.0f;
    wsI[b]       = cxi;
    wsI[128 + b] = cyi;
    wsI[256 + b] = czi;
    wsI[384 + b] = rx;
    wsI[512 + b] = rz;
    wsI[640 + b] = valid;
    wsF[768 + b]  = 1.0f / (2.0f * sx * sx);
    wsF[896 + b]  = 1.0f / (2.0f * sx * sx);
    wsF[1024 + b] = 1.0f / (2.0f * sz * sz);
}

// hmv stored as [z][gx][gy]  (== hm3d [d][h][w] broadcast layout)
__global__ void k_heatmap(const int* __restrict__ wsI, const float* __restrict__ wsF,
                          float* __restrict__ hmv, float* __restrict__ partial, int N) {
    int i = blockIdx.x * 256 + threadIdx.x;
    int y = i & 127, x = (i >> 7) & 127, zc = i >> 14;
    float m = 0.0f;
    for (int b = 0; b < N; ++b) {
        if (!wsI[640 + b]) continue;
        int rx = wsI[384 + b];
        int dx = x - wsI[b];
        if (dx > rx || dx < -rx) continue;
        int dy = y - wsI[128 + b];
        if (dy > rx || dy < -rx) continue;
        int rz = wsI[512 + b];
        int dz = zc - wsI[256 + b];
        if (dz > rz || dz < -rz) continue;
        float e = (float)(dx * dx) * wsF[768 + b]
                + (float)(dy * dy) * wsF[896 + b]
                + (float)(dz * dz) * wsF[1024 + b];
        float g = expf(-e);
        if (g >= EPS32) m = fmaxf(m, g);
    }
    hmv[i] = m;
    __shared__ float sm[256];
    sm[threadIdx.x] = m;
    __syncthreads();
    for (int s = 128; s > 0; s >>= 1) {
        if (threadIdx.x < s) sm[threadIdx.x] += sm[threadIdx.x + s];
        __syncthreads();
    }
    if (threadIdx.x == 0) partial[blockIdx.x] = sm[0];
}

__global__ void k_scale(const float* __restrict__ partial, float* __restrict__ scale) {
    __shared__ float sm[128];
    sm[threadIdx.x] = partial[threadIdx.x];
    __syncthreads();
    for (int s = 64; s > 0; s >>= 1) {
        if (threadIdx.x < s) sm[threadIdx.x] += sm[threadIdx.x + s];
        __syncthreads();
    }
    if (threadIdx.x == 0) scale[0] = 10.0f / (sm[0] + 1e-4f);
}

// pooled[c][d][h][w] = (1/8) * sum student[c, {zl,zl+1}, {2h,2h+1}, {2w,2w+1}], zl = d?5:1
__global__ void k_pool(const float* __restrict__ S, float* __restrict__ P) {
    int i = blockIdx.x * 256 + threadIdx.x;  // < 64*2*128*128
    int w = i & 127, h = (i >> 7) & 127, d = (i >> 14) & 1, c = i >> 15;
    int zl = d ? 5 : 1;
    const float2* S2 = (const float2*)S;
    long base = ((long)(c * 8 + zl) * 256 + 2 * h) * 128 + w;  // float2 units; row=128 float2
    float2 a = S2[base];
    float2 b = S2[base + 128];
    float2 e = S2[base + 32768];          // next z plane = 256*256 floats = 32768 float2
    float2 f = S2[base + 32768 + 128];
    P[i] = (((a.x + a.y) + (b.x + b.y)) + ((e.x + e.y) + (f.x + f.y))) * 0.125f;
}

// out[o,s] = |dot(W[o,:], P[:,s]) + B[o] - T[o,s]| * hmv[s] * scale
__global__ void k_final(const float* __restrict__ P, const float* __restrict__ T,
                        const float* __restrict__ W, const float* __restrict__ B,
                        const float* __restrict__ hmv, const float* __restrict__ scale,
                        float* __restrict__ out) {
    int s = blockIdx.x * 256 + threadIdx.x;
    int o0 = blockIdx.y * 16;
    float p[64];
#pragma unroll
    for (int c = 0; c < 64; ++c) p[c] = P[c * NSP + s];
    float hmw = hmv[s] * scale[0];
#pragma unroll 4
    for (int oo = 0; oo < 16; ++oo) {
        int o = o0 + oo;
        float acc = B[o];
#pragma unroll
        for (int c = 0; c < 64; ++c) acc += W[o * 64 + c] * p[c];
        float tv = T[o * NSP + s];
        out[o * NSP + s] = fabsf(acc - tv) * hmw;
    }
}

// Fallback if ws too small for the pooled buffer: pool inline, o-groups of 64.
__global__ void k_final_fused(const float* __restrict__ S, const float* __restrict__ T,
                              const float* __restrict__ W, const float* __restrict__ B,
                              const float* __restrict__ hmv, const float* __restrict__ scale,
                              float* __restrict__ out) {
    int s = blockIdx.x * 256 + threadIdx.x;
    int w = s & 127, h = (s >> 7) & 127, d = s >> 14;
    int zl = d ? 5 : 1;
    const float2* S2 = (const float2*)S;
    float p[64];
#pragma unroll
    for (int c = 0; c < 64; ++c) {
        long base = ((long)(c * 8 + zl) * 256 + 2 * h) * 128 + w;
        float2 a = S2[base];
        float2 b = S2[base + 128];
        float2 e = S2[base + 32768];
        float2 f = S2[base + 32768 + 128];
        p[c] = (((a.x + a.y) + (b.x + b.y)) + ((e.x + e.y) + (f.x + f.y))) * 0.125f;
    }
    float hmw = hmv[s] * scale[0];
    int o0 = blockIdx.y * 64;
    for (int oo = 0; oo < 64; ++oo) {
        int o = o0 + oo;
        float acc = B[o];
#pragma unroll
        for (int c = 0; c < 64; ++c) acc += W[o * 64 + c] * p[c];
        float tv = T[o * NSP + s];
        out[o * NSP + s] = fabsf(acc - tv) * hmw;
    }
}

extern "C" void kernel_launch(void* const* d_in, const int* in_sizes, int n_in,
                              void* d_out, int out_size, void* d_ws, size_t ws_size,
                              hipStream_t stream) {
    const float* boxes   = (const float*)d_in[0];
    // d_in[1] = gt_labels_3d (unused by the reference output)
    const float* teacher = (const float*)d_in[2];
    const float* student = (const float*)d_in[3];
    const float* conv_w  = (const float*)d_in[4];
    const float* conv_b  = (const float*)d_in[5];
    float* out = (float*)d_out;

    int N = in_sizes[0] / 9;
    if (N > 128) N = 128;

    int*   wsI     = (int*)d_ws;
    float* wsF     = (float*)d_ws;
    float* partial = wsF + 1152;
    float* scale   = wsF + 1280;
    float* hmv     = wsF + 2048;
    float* pooled  = wsF + 65536;

    k_params<<<1, 128, 0, stream>>>(boxes, N, wsI, wsF);
    k_heatmap<<<128, 256, 0, stream>>>(wsI, wsF, hmv, partial, N);
    k_scale<<<1, 128, 0, stream>>>(partial, scale);

    const size_t need = (size_t)(65536 + 64 * NSP) * sizeof(float);
    if (ws_size >= need) {
        k_pool<<<(64 * NSP) / 256, 256, 0, stream>>>(student, pooled);
        k_final<<<dim3(NSP / 256, 8), 256, 0, stream>>>(pooled, teacher, conv_w, conv_b,
                                                        hmv, scale, out);
    } else {
        k_final_fused<<<dim3(NSP / 256, 2), 256, 0, stream>>>(student, teacher, conv_w, conv_b,
                                                              hmv, scale, out);
    }
}

// Round 2
// 249.791 us; speedup vs baseline: 1.0897x; 1.0897x over previous
//
#include <hip/hip_runtime.h>
#include <math.h>

#define EPS32 1.1920928955078125e-07f
#define NSP 32768          // 2*128*128 spatial positions
#define HB 128             // heatmap blocks
#define PB 4096            // pool blocks (64ch * 2d * 128h * 64 float4-pairs / 256 thr)

// ---------------- ws layout (float units) ----------------
// 0     : partial[128]
// 1024  : hmv[32768]
// 65536 : pooled[64*32768]

__device__ __forceinline__ float gauss_radius(float h, float w) {
#pragma clang fp contract(off)
    const float mo = 0.1f;
    float b1 = h + w;
    float c1 = w * h * (1.0f - mo) / (1.0f + mo);
    float r1 = (b1 + sqrtf(fmaxf(b1 * b1 - 4.0f * c1, 0.0f))) / 2.0f;
    float b2 = 2.0f * (h + w);
    float c2 = (1.0f - mo) * w * h;
    float r2 = (b2 + sqrtf(fmaxf(b2 * b2 - 16.0f * c2, 0.0f))) / 2.0f;
    float b3 = -2.0f * mo * (h + w);
    float c3 = (mo - 1.0f) * w * h;
    float r3 = (b3 + sqrtf(fmaxf(b3 * b3 - 16.0f * mo * c3, 0.0f))) / 2.0f;
    return fminf(fminf(r1, r2), r3);
}

// blocks [0,HB): heatmap (+ in-LDS box params + per-block partial sum)
// blocks [HB, HB+PB): 2x2x2 average pool of student with float4 loads
__global__ void k_stage1(const float* __restrict__ boxes, int N,
                         const float* __restrict__ S,
                         float* __restrict__ P,
                         float* __restrict__ hmv,
                         float* __restrict__ partial) {
    int bx = blockIdx.x;
    int tid = threadIdx.x;

    if (bx < HB) {
        // ---- per-block box param computation (redundant, cheap) ----
        __shared__ int   s_cxi[128], s_cyi[128], s_czi[128], s_rx[128], s_rz[128];
        __shared__ float s_ix[128], s_iz[128];
        if (tid < N) {
#pragma clang fp contract(off)
            int b = tid;
            float x = boxes[b * 9 + 0];
            float y = boxes[b * 9 + 1];
            float z = boxes[b * 9 + 2];
            float wf = boxes[b * 9 + 3] / 0.1f / 8.0f;
            float lf = boxes[b * 9 + 4] / 0.1f / 8.0f;
            float hf = boxes[b * 9 + 5] / 0.2f / 8.0f;
            float r_xy = gauss_radius(lf, wf);
            float r_z  = fmaxf(gauss_radius(lf, hf), gauss_radius(wf, hf));
            int rx = max(2, (int)truncf(r_xy / 0.4f));
            int rz = max(2, (int)truncf(r_z / 1.0f));
            float cx = (x + 51.2f) / 0.4f;
            float cy = (y + 51.2f) / 0.4f;
            float cz = (z + 5.0f) / 1.0f;
            int cxi = (int)cx, cyi = (int)cy, czi = (int)cz;
            int valid = (wf > 0.0f) && (lf > 0.0f) &&
                        cxi >= 0 && cxi < 128 && cyi >= 0 && cyi < 128 &&
                        czi >= 0 && czi <= 1;
            float sx = (2.0f * (float)rx + 1.0f) / 6.0f;
            float sz = (2.0f * (float)rz + 1.0f) / 6.0f;
            s_cxi[b] = cxi;
            s_cyi[b] = cyi;
            s_czi[b] = czi;
            s_rx[b]  = valid ? rx : -1;   // rx=-1 makes window test always fail
            s_rz[b]  = rz;
            s_ix[b]  = 1.0f / (2.0f * sx * sx);
            s_iz[b]  = 1.0f / (2.0f * sz * sz);
        }
        __syncthreads();

        int i = bx * 256 + tid;
        int y = i & 127, x = (i >> 7) & 127, zc = i >> 14;
        float m = 0.0f;
        for (int b = 0; b < N; ++b) {
            int rx = s_rx[b];
            int dx = x - s_cxi[b];
            if (dx > rx || dx < -rx) continue;
            int dy = y - s_cyi[b];
            if (dy > rx || dy < -rx) continue;
            int rz = s_rz[b];
            int dz = zc - s_czi[b];
            if (dz > rz || dz < -rz) continue;
            float e = (float)(dx * dx + dy * dy) * s_ix[b]
                    + (float)(dz * dz) * s_iz[b];
            float g = expf(-e);
            if (g >= EPS32) m = fmaxf(m, g);
        }
        hmv[i] = m;
        __shared__ float sm[256];
        sm[tid] = m;
        __syncthreads();
        for (int s = 128; s > 0; s >>= 1) {
            if (tid < s) sm[tid] += sm[tid + s];
            __syncthreads();
        }
        if (tid == 0) partial[bx] = sm[0];
    } else {
        // ---- pool: each thread produces 2 pooled outputs from 4 float4 loads ----
        int j = (bx - HB) * 256 + tid;        // < 64*2*128*64 = 1048576
        int wp = j & 63;                       // float4 column (row = 64 float4)
        int h  = (j >> 6) & 127;
        int d  = (j >> 13) & 1;
        int c  = j >> 14;
        int zl = d ? 5 : 1;
        const float4* S4 = (const float4*)S;
        long base = ((long)(c * 8 + zl) * 256 + 2 * h) * 64 + wp;
        float4 a = S4[base];
        float4 b = S4[base + 64];
        float4 e = S4[base + 16384];           // next z plane = 65536 floats
        float4 f = S4[base + 16384 + 64];
        float2 r;
        r.x = (((a.x + a.y) + (b.x + b.y)) + ((e.x + e.y) + (f.x + f.y))) * 0.125f;
        r.y = (((a.z + a.w) + (b.z + b.w)) + ((e.z + e.w) + (f.z + f.w))) * 0.125f;
        ((float2*)P)[j] = r;
    }
}

// out[o,s] = |dot(W[o,:], P[:,s]) + B[o] - T[o,s]| * hmv[s] * 10/(sum+1e-4)
__global__ void k_final(const float* __restrict__ P, const float* __restrict__ T,
                        const float* __restrict__ W, const float* __restrict__ Bb,
                        const float* __restrict__ hmv, const float* __restrict__ partial,
                        float* __restrict__ out) {
    __shared__ float s_scale;
    int tid = threadIdx.x;
    if (tid < 64) {
        float v = partial[tid] + partial[tid + 64];
        for (int off = 32; off > 0; off >>= 1) v += __shfl_down(v, off, 64);
        if (tid == 0) s_scale = 10.0f / (v + 1e-4f);
    }
    __syncthreads();

    int s = blockIdx.x * 256 + tid;
    float p[64];
#pragma unroll
    for (int c = 0; c < 64; ++c) p[c] = P[c * NSP + s];
    float hmw = hmv[s] * s_scale;
    int o0 = blockIdx.y * 32;
#pragma unroll 4
    for (int oo = 0; oo < 32; ++oo) {
        int o = o0 + oo;
        float acc = Bb[o];
#pragma unroll
        for (int c = 0; c < 64; ++c) acc += W[o * 64 + c] * p[c];
        out[o * NSP + s] = fabsf(acc - T[o * NSP + s]) * hmw;
    }
}

// Fallback (ws too small for pooled buffer): pool inline, all 128 o per thread-pair.
__global__ void k_final_fused(const float* __restrict__ S, const float* __restrict__ T,
                              const float* __restrict__ W, const float* __restrict__ Bb,
                              const float* __restrict__ hmv, const float* __restrict__ partial,
                              float* __restrict__ out) {
    __shared__ float s_scale;
    int tid = threadIdx.x;
    if (tid < 64) {
        float v = partial[tid] + partial[tid + 64];
        for (int off = 32; off > 0; off >>= 1) v += __shfl_down(v, off, 64);
        if (tid == 0) s_scale = 10.0f / (v + 1e-4f);
    }
    __syncthreads();
    int s = blockIdx.x * 256 + tid;
    int w = s & 127, h = (s >> 7) & 127, d = s >> 14;
    int zl = d ? 5 : 1;
    const float2* S2 = (const float2*)S;
    float p[64];
#pragma unroll
    for (int c = 0; c < 64; ++c) {
        long base = ((long)(c * 8 + zl) * 256 + 2 * h) * 128 + w;
        float2 a = S2[base];
        float2 b = S2[base + 128];
        float2 e = S2[base + 32768];
        float2 f = S2[base + 32768 + 128];
        p[c] = (((a.x + a.y) + (b.x + b.y)) + ((e.x + e.y) + (f.x + f.y))) * 0.125f;
    }
    float hmw = hmv[s] * s_scale;
    int o0 = blockIdx.y * 64;
    for (int oo = 0; oo < 64; ++oo) {
        int o = o0 + oo;
        float acc = Bb[o];
#pragma unroll
        for (int c = 0; c < 64; ++c) acc += W[o * 64 + c] * p[c];
        out[o * NSP + s] = fabsf(acc - T[o * NSP + s]) * hmw;
    }
}

extern "C" void kernel_launch(void* const* d_in, const int* in_sizes, int n_in,
                              void* d_out, int out_size, void* d_ws, size_t ws_size,
                              hipStream_t stream) {
    const float* boxes   = (const float*)d_in[0];
    // d_in[1] = gt_labels_3d (unused by the reference output)
    const float* teacher = (const float*)d_in[2];
    const float* student = (const float*)d_in[3];
    const float* conv_w  = (const float*)d_in[4];
    const float* conv_b  = (const float*)d_in[5];
    float* out = (float*)d_out;

    int N = in_sizes[0] / 9;
    if (N > 128) N = 128;

    float* wsF     = (float*)d_ws;
    float* partial = wsF;
    float* hmv     = wsF + 1024;
    float* pooled  = wsF + 65536;

    const size_t need = (size_t)(65536 + 64 * NSP) * sizeof(float);
    if (ws_size >= need) {
        k_stage1<<<HB + PB, 256, 0, stream>>>(boxes, N, student, pooled, hmv, partial);
        k_final<<<dim3(NSP / 256, 4), 256, 0, stream>>>(pooled, teacher, conv_w, conv_b,
                                                        hmv, partial, out);
    } else {
        // heatmap-only stage (no pool blocks), then fused final
        k_stage1<<<HB, 256, 0, stream>>>(boxes, N, student, /*P unused*/ hmv, hmv, partial);
        k_final_fused<<<dim3(NSP / 256, 2), 256, 0, stream>>>(student, teacher, conv_w, conv_b,
                                                              hmv, partial, out);
    }
}

// Round 3
// 238.997 us; speedup vs baseline: 1.1389x; 1.0452x over previous
//
#include <hip/hip_runtime.h>
#include <math.h>

#define EPS32 1.1920928955078125e-07f
#define NSP 32768          // 2*128*128 spatial positions
#define HB 128             // heatmap blocks
#define PB 4096            // pool blocks (64ch * 2d * 128h * 64 float4-pairs / 256 thr)

// ---------------- ws layout (float units) ----------------
// 0     : partial[128]
// 1024  : hmv[32768]
// 65536 : pooled[64*32768]

__device__ __forceinline__ float gauss_radius(float h, float w) {
#pragma clang fp contract(off)
    const float mo = 0.1f;
    float b1 = h + w;
    float c1 = w * h * (1.0f - mo) / (1.0f + mo);
    float r1 = (b1 + sqrtf(fmaxf(b1 * b1 - 4.0f * c1, 0.0f))) / 2.0f;
    float b2 = 2.0f * (h + w);
    float c2 = (1.0f - mo) * w * h;
    float r2 = (b2 + sqrtf(fmaxf(b2 * b2 - 16.0f * c2, 0.0f))) / 2.0f;
    float b3 = -2.0f * mo * (h + w);
    float c3 = (mo - 1.0f) * w * h;
    float r3 = (b3 + sqrtf(fmaxf(b3 * b3 - 16.0f * mo * c3, 0.0f))) / 2.0f;
    return fminf(fminf(r1, r2), r3);
}

// blocks [0,HB): heatmap (+ in-LDS box params + per-block partial sum)
// blocks [HB, HB+PB): 2x2x2 average pool of student with float4 loads
__global__ void k_stage1(const float* __restrict__ boxes, int N,
                         const float* __restrict__ S,
                         float* __restrict__ P,
                         float* __restrict__ hmv,
                         float* __restrict__ partial) {
    int bx = blockIdx.x;
    int tid = threadIdx.x;

    if (bx < HB) {
        __shared__ int   s_cxi[128], s_cyi[128], s_czi[128], s_rx[128], s_rz[128];
        __shared__ float s_ix[128], s_iz[128];
        if (tid < N) {
#pragma clang fp contract(off)
            int b = tid;
            float x = boxes[b * 9 + 0];
            float y = boxes[b * 9 + 1];
            float z = boxes[b * 9 + 2];
            float wf = boxes[b * 9 + 3] / 0.1f / 8.0f;
            float lf = boxes[b * 9 + 4] / 0.1f / 8.0f;
            float hf = boxes[b * 9 + 5] / 0.2f / 8.0f;
            float r_xy = gauss_radius(lf, wf);
            float r_z  = fmaxf(gauss_radius(lf, hf), gauss_radius(wf, hf));
            int rx = max(2, (int)truncf(r_xy / 0.4f));
            int rz = max(2, (int)truncf(r_z / 1.0f));
            float cx = (x + 51.2f) / 0.4f;
            float cy = (y + 51.2f) / 0.4f;
            float cz = (z + 5.0f) / 1.0f;
            int cxi = (int)cx, cyi = (int)cy, czi = (int)cz;
            int valid = (wf > 0.0f) && (lf > 0.0f) &&
                        cxi >= 0 && cxi < 128 && cyi >= 0 && cyi < 128 &&
                        czi >= 0 && czi <= 1;
            float sx = (2.0f * (float)rx + 1.0f) / 6.0f;
            float sz = (2.0f * (float)rz + 1.0f) / 6.0f;
            s_cxi[b] = cxi;
            s_cyi[b] = cyi;
            s_czi[b] = czi;
            s_rx[b]  = valid ? rx : -1;   // rx=-1 makes window test always fail
            s_rz[b]  = rz;
            s_ix[b]  = 1.0f / (2.0f * sx * sx);
            s_iz[b]  = 1.0f / (2.0f * sz * sz);
        }
        __syncthreads();

        int i = bx * 256 + tid;
        int y = i & 127, x = (i >> 7) & 127, zc = i >> 14;
        float m = 0.0f;
        for (int b = 0; b < N; ++b) {
            int rx = s_rx[b];
            int dx = x - s_cxi[b];
            if (dx > rx || dx < -rx) continue;
            int dy = y - s_cyi[b];
            if (dy > rx || dy < -rx) continue;
            int rz = s_rz[b];
            int dz = zc - s_czi[b];
            if (dz > rz || dz < -rz) continue;
            float e = (float)(dx * dx + dy * dy) * s_ix[b]
                    + (float)(dz * dz) * s_iz[b];
            float g = expf(-e);
            if (g >= EPS32) m = fmaxf(m, g);
        }
        hmv[i] = m;
        __shared__ float sm[256];
        sm[tid] = m;
        __syncthreads();
        for (int s = 128; s > 0; s >>= 1) {
            if (tid < s) sm[tid] += sm[tid + s];
            __syncthreads();
        }
        if (tid == 0) partial[bx] = sm[0];
    } else {
        int j = (bx - HB) * 256 + tid;        // < 64*2*128*64 = 1048576
        int wp = j & 63;                       // float4 column (row = 64 float4)
        int h  = (j >> 6) & 127;
        int d  = (j >> 13) & 1;
        int c  = j >> 14;
        int zl = d ? 5 : 1;
        const float4* S4 = (const float4*)S;
        long base = ((long)(c * 8 + zl) * 256 + 2 * h) * 64 + wp;
        float4 a = S4[base];
        float4 b = S4[base + 64];
        float4 e = S4[base + 16384];           // next z plane = 65536 floats
        float4 f = S4[base + 16384 + 64];
        float2 r;
        r.x = (((a.x + a.y) + (b.x + b.y)) + ((e.x + e.y) + (f.x + f.y))) * 0.125f;
        r.y = (((a.z + a.w) + (b.z + b.w)) + ((e.z + e.w) + (f.z + f.w))) * 0.125f;
        ((float2*)P)[j] = r;
    }
}

// out[o,s] = |dot(W[o,:], P[:,s]) + B[o] - T[o,s]| * hmv[s] * 10/(sum+1e-4)
// __launch_bounds__(256, 2): VGPR cap 256 so p[64] stays register-resident
// (R1 failure mode: default heuristic chose 64 VGPRs -> p[] rematerialized
//  from L2 inside the o-loop -> latency-bound 82 us).
__global__ __launch_bounds__(256, 2)
void k_final(const float* __restrict__ P, const float* __restrict__ T,
             const float* __restrict__ W, const float* __restrict__ Bb,
             const float* __restrict__ hmv, const float* __restrict__ partial,
             float* __restrict__ out) {
    __shared__ float s_scale;
    int tid = threadIdx.x;
    if (tid < 64) {
        float v = partial[tid] + partial[tid + 64];
        for (int off = 32; off > 0; off >>= 1) v += __shfl_down(v, off, 64);
        if (tid == 0) s_scale = 10.0f / (v + 1e-4f);
    }
    __syncthreads();

    int s = blockIdx.x * 256 + tid;
    int o0 = blockIdx.y * 32;

    const float* Pv = P + s;
    float p[64];
#pragma unroll
    for (int c = 0; c < 64; ++c) p[c] = Pv[c * NSP];

    float hmw = hmv[s] * s_scale;

    // one live accumulator per oo (unroll 4 for ILP, not 32 -> keeps live set ~90 VGPRs)
#pragma unroll 4
    for (int oo = 0; oo < 32; ++oo) {
        int o = o0 + oo;
        const float* w = W + o * 64;   // wave-uniform -> scalar loads
        float acc = Bb[o];
#pragma unroll
        for (int c = 0; c < 64; ++c) acc = fmaf(w[c], p[c], acc);
        out[o * NSP + s] = fabsf(acc - T[o * NSP + s]) * hmw;
    }
}

// Fallback (ws too small for pooled buffer): pool inline, o-groups of 64.
__global__ __launch_bounds__(256, 2)
void k_final_fused(const float* __restrict__ S, const float* __restrict__ T,
                   const float* __restrict__ W, const float* __restrict__ Bb,
                   const float* __restrict__ hmv, const float* __restrict__ partial,
                   float* __restrict__ out) {
    __shared__ float s_scale;
    int tid = threadIdx.x;
    if (tid < 64) {
        float v = partial[tid] + partial[tid + 64];
        for (int off = 32; off > 0; off >>= 1) v += __shfl_down(v, off, 64);
        if (tid == 0) s_scale = 10.0f / (v + 1e-4f);
    }
    __syncthreads();
    int s = blockIdx.x * 256 + tid;
    int w = s & 127, h = (s >> 7) & 127, d = s >> 14;
    int zl = d ? 5 : 1;
    const float2* S2 = (const float2*)S;
    float p[64];
#pragma unroll
    for (int c = 0; c < 64; ++c) {
        long base = ((long)(c * 8 + zl) * 256 + 2 * h) * 128 + w;
        float2 a = S2[base];
        float2 b = S2[base + 128];
        float2 e = S2[base + 32768];
        float2 f = S2[base + 32768 + 128];
        p[c] = (((a.x + a.y) + (b.x + b.y)) + ((e.x + e.y) + (f.x + f.y))) * 0.125f;
    }
    float hmw = hmv[s] * s_scale;
    int o0 = blockIdx.y * 64;
#pragma unroll 4
    for (int oo = 0; oo < 64; ++oo) {
        int o = o0 + oo;
        const float* wr = W + o * 64;
        float acc = Bb[o];
#pragma unroll
        for (int c = 0; c < 64; ++c) acc = fmaf(wr[c], p[c], acc);
        out[o * NSP + s] = fabsf(acc - T[o * NSP + s]) * hmw;
    }
}

extern "C" void kernel_launch(void* const* d_in, const int* in_sizes, int n_in,
                              void* d_out, int out_size, void* d_ws, size_t ws_size,
                              hipStream_t stream) {
    const float* boxes   = (const float*)d_in[0];
    // d_in[1] = gt_labels_3d (unused by the reference output)
    const float* teacher = (const float*)d_in[2];
    const float* student = (const float*)d_in[3];
    const float* conv_w  = (const float*)d_in[4];
    const float* conv_b  = (const float*)d_in[5];
    float* out = (float*)d_out;

    int N = in_sizes[0] / 9;
    if (N > 128) N = 128;

    float* wsF     = (float*)d_ws;
    float* partial = wsF;
    float* hmv     = wsF + 1024;
    float* pooled  = wsF + 65536;

    const size_t need = (size_t)(65536 + 64 * NSP) * sizeof(float);
    if (ws_size >= need) {
        k_stage1<<<HB + PB, 256, 0, stream>>>(boxes, N, student, pooled, hmv, partial);
        k_final<<<dim3(NSP / 256, 4), 256, 0, stream>>>(pooled, teacher, conv_w, conv_b,
                                                        hmv, partial, out);
    } else {
        k_stage1<<<HB, 256, 0, stream>>>(boxes, N, student, /*P unused*/ hmv, hmv, partial);
        k_final_fused<<<dim3(NSP / 256, 2), 256, 0, stream>>>(student, teacher, conv_w, conv_b,
                                                              hmv, partial, out);
    }
}

// Round 4
// 212.005 us; speedup vs baseline: 1.2840x; 1.1273x over previous
//
#include <hip/hip_runtime.h>
#include <math.h>

#define EPS32 1.1920928955078125e-07f
#define NSP 32768          // 2*128*128 spatial positions
#define HB 128             // heatmap blocks
#define PB 4096            // pool blocks (64ch * 2d * 128h * 64 float4-pairs / 256 thr)

// ---------------- ws layout (float units) ----------------
// 0     : partial[128]
// 1024  : hmv[32768]
// 65536 : pooled[64*32768]

__device__ __forceinline__ float gauss_radius(float h, float w) {
#pragma clang fp contract(off)
    const float mo = 0.1f;
    float b1 = h + w;
    float c1 = w * h * (1.0f - mo) / (1.0f + mo);
    float r1 = (b1 + sqrtf(fmaxf(b1 * b1 - 4.0f * c1, 0.0f))) / 2.0f;
    float b2 = 2.0f * (h + w);
    float c2 = (1.0f - mo) * w * h;
    float r2 = (b2 + sqrtf(fmaxf(b2 * b2 - 16.0f * c2, 0.0f))) / 2.0f;
    float b3 = -2.0f * mo * (h + w);
    float c3 = (mo - 1.0f) * w * h;
    float r3 = (b3 + sqrtf(fmaxf(b3 * b3 - 16.0f * mo * c3, 0.0f))) / 2.0f;
    return fminf(fminf(r1, r2), r3);
}

// blocks [0,HB): heatmap (+ in-LDS box params + per-block partial sum)
// blocks [HB, HB+PB): 2x2x2 average pool of student with float4 loads
__global__ void k_stage1(const float* __restrict__ boxes, int N,
                         const float* __restrict__ S,
                         float* __restrict__ P,
                         float* __restrict__ hmv,
                         float* __restrict__ partial) {
    int bx = blockIdx.x;
    int tid = threadIdx.x;

    if (bx < HB) {
        __shared__ int   s_cxi[128], s_cyi[128], s_czi[128], s_rx[128], s_rz[128];
        __shared__ float s_ix[128], s_iz[128];
        if (tid < N) {
#pragma clang fp contract(off)
            int b = tid;
            float x = boxes[b * 9 + 0];
            float y = boxes[b * 9 + 1];
            float z = boxes[b * 9 + 2];
            float wf = boxes[b * 9 + 3] / 0.1f / 8.0f;
            float lf = boxes[b * 9 + 4] / 0.1f / 8.0f;
            float hf = boxes[b * 9 + 5] / 0.2f / 8.0f;
            float r_xy = gauss_radius(lf, wf);
            float r_z  = fmaxf(gauss_radius(lf, hf), gauss_radius(wf, hf));
            int rx = max(2, (int)truncf(r_xy / 0.4f));
            int rz = max(2, (int)truncf(r_z / 1.0f));
            float cx = (x + 51.2f) / 0.4f;
            float cy = (y + 51.2f) / 0.4f;
            float cz = (z + 5.0f) / 1.0f;
            int cxi = (int)cx, cyi = (int)cy, czi = (int)cz;
            int valid = (wf > 0.0f) && (lf > 0.0f) &&
                        cxi >= 0 && cxi < 128 && cyi >= 0 && cyi < 128 &&
                        czi >= 0 && czi <= 1;
            float sx = (2.0f * (float)rx + 1.0f) / 6.0f;
            float sz = (2.0f * (float)rz + 1.0f) / 6.0f;
            s_cxi[b] = cxi;
            s_cyi[b] = cyi;
            s_czi[b] = czi;
            s_rx[b]  = valid ? rx : -1;   // rx=-1 makes window test always fail
            s_rz[b]  = rz;
            s_ix[b]  = 1.0f / (2.0f * sx * sx);
            s_iz[b]  = 1.0f / (2.0f * sz * sz);
        }
        __syncthreads();

        int i = bx * 256 + tid;
        int y = i & 127, x = (i >> 7) & 127, zc = i >> 14;
        float m = 0.0f;
        for (int b = 0; b < N; ++b) {
            int rx = s_rx[b];
            int dx = x - s_cxi[b];
            if (dx > rx || dx < -rx) continue;
            int dy = y - s_cyi[b];
            if (dy > rx || dy < -rx) continue;
            int rz = s_rz[b];
            int dz = zc - s_czi[b];
            if (dz > rz || dz < -rz) continue;
            float e = (float)(dx * dx + dy * dy) * s_ix[b]
                    + (float)(dz * dz) * s_iz[b];
            float g = expf(-e);
            if (g >= EPS32) m = fmaxf(m, g);
        }
        hmv[i] = m;
        __shared__ float sm[256];
        sm[tid] = m;
        __syncthreads();
        for (int s = 128; s > 0; s >>= 1) {
            if (tid < s) sm[tid] += sm[tid + s];
            __syncthreads();
        }
        if (tid == 0) partial[bx] = sm[0];
    } else {
        int j = (bx - HB) * 256 + tid;        // < 64*2*128*64 = 1048576
        int wp = j & 63;                       // float4 column (row = 64 float4)
        int h  = (j >> 6) & 127;
        int d  = (j >> 13) & 1;
        int c  = j >> 14;
        int zl = d ? 5 : 1;
        const float4* S4 = (const float4*)S;
        long base = ((long)(c * 8 + zl) * 256 + 2 * h) * 64 + wp;
        float4 a = S4[base];
        float4 b = S4[base + 64];
        float4 e = S4[base + 16384];           // next z plane = 65536 floats
        float4 f = S4[base + 16384 + 64];
        float2 r;
        r.x = (((a.x + a.y) + (b.x + b.y)) + ((e.x + e.y) + (f.x + f.y))) * 0.125f;
        r.y = (((a.z + a.w) + (b.z + b.w)) + ((e.z + e.w) + (f.z + f.w))) * 0.125f;
        ((float2*)P)[j] = r;
    }
}

// out[o,s] = |dot(W[o,:], P[:,s]) + B[o] - T[o,s]| * hmv[s] * 10/(sum+1e-4)
//
// c-OUTER / o-INNER: live set is acc[16] + 8 streamed pc values (~40 VGPRs).
// No p[64] array -> structurally immune to the R2 spill failure mode
// (R2: VGPR_Count=64, WRITE_SIZE 39.2MB vs 16.8MB expected = scratch spill).
// Grid 128x8 = 1024 blocks = 4 waves/SIMD; pooled re-read x8 (67MB) served
// from L3 (pooled is 8.4MB, written by k_stage1 immediately before).
__global__ __launch_bounds__(256, 4)
void k_final(const float* __restrict__ P, const float* __restrict__ T,
             const float* __restrict__ W, const float* __restrict__ Bb,
             const float* __restrict__ hmv, const float* __restrict__ partial,
             float* __restrict__ out) {
    __shared__ float s_scale;
    int tid = threadIdx.x;
    if (tid < 64) {
        float v = partial[tid] + partial[tid + 64];
        for (int off = 32; off > 0; off >>= 1) v += __shfl_down(v, off, 64);
        if (tid == 0) s_scale = 10.0f / (v + 1e-4f);
    }
    __syncthreads();

    int s = blockIdx.x * 256 + tid;
    int o0 = blockIdx.y * 16;

    float acc[16];
#pragma unroll
    for (int oo = 0; oo < 16; ++oo) acc[oo] = Bb[o0 + oo];

    const float* Pv = P + s;
    const float* Wv = W + o0 * 64;      // wave-uniform -> scalar k-cache loads
#pragma unroll 8
    for (int c = 0; c < 64; ++c) {
        float pc = Pv[(long)c * NSP];
#pragma unroll
        for (int oo = 0; oo < 16; ++oo)
            acc[oo] = fmaf(Wv[oo * 64 + c], pc, acc[oo]);
    }

    float hmw = hmv[s] * s_scale;
#pragma unroll
    for (int oo = 0; oo < 16; ++oo) {
        int o = o0 + oo;
        out[(long)o * NSP + s] = fabsf(acc[oo] - T[(long)o * NSP + s]) * hmw;
    }
}

// Fallback (ws too small for pooled buffer): pool inline, c-outer as well.
__global__ __launch_bounds__(256, 2)
void k_final_fused(const float* __restrict__ S, const float* __restrict__ T,
                   const float* __restrict__ W, const float* __restrict__ Bb,
                   const float* __restrict__ hmv, const float* __restrict__ partial,
                   float* __restrict__ out) {
    __shared__ float s_scale;
    int tid = threadIdx.x;
    if (tid < 64) {
        float v = partial[tid] + partial[tid + 64];
        for (int off = 32; off > 0; off >>= 1) v += __shfl_down(v, off, 64);
        if (tid == 0) s_scale = 10.0f / (v + 1e-4f);
    }
    __syncthreads();
    int s = blockIdx.x * 256 + tid;
    int w = s & 127, h = (s >> 7) & 127, d = s >> 14;
    int zl = d ? 5 : 1;
    const float2* S2 = (const float2*)S;
    int o0 = blockIdx.y * 16;
    float acc[16];
#pragma unroll
    for (int oo = 0; oo < 16; ++oo) acc[oo] = Bb[o0 + oo];
    const float* Wv = W + o0 * 64;
#pragma unroll 4
    for (int c = 0; c < 64; ++c) {
        long base = ((long)(c * 8 + zl) * 256 + 2 * h) * 128 + w;
        float2 a = S2[base];
        float2 b = S2[base + 128];
        float2 e = S2[base + 32768];
        float2 f = S2[base + 32768 + 128];
        float pc = (((a.x + a.y) + (b.x + b.y)) + ((e.x + e.y) + (f.x + f.y))) * 0.125f;
#pragma unroll
        for (int oo = 0; oo < 16; ++oo)
            acc[oo] = fmaf(Wv[oo * 64 + c], pc, acc[oo]);
    }
    float hmw = hmv[s] * s_scale;
#pragma unroll
    for (int oo = 0; oo < 16; ++oo) {
        int o = o0 + oo;
        out[(long)o * NSP + s] = fabsf(acc[oo] - T[(long)o * NSP + s]) * hmw;
    }
}

extern "C" void kernel_launch(void* const* d_in, const int* in_sizes, int n_in,
                              void* d_out, int out_size, void* d_ws, size_t ws_size,
                              hipStream_t stream) {
    const float* boxes   = (const float*)d_in[0];
    // d_in[1] = gt_labels_3d (unused by the reference output)
    const float* teacher = (const float*)d_in[2];
    const float* student = (const float*)d_in[3];
    const float* conv_w  = (const float*)d_in[4];
    const float* conv_b  = (const float*)d_in[5];
    float* out = (float*)d_out;

    int N = in_sizes[0] / 9;
    if (N > 128) N = 128;

    float* wsF     = (float*)d_ws;
    float* partial = wsF;
    float* hmv     = wsF + 1024;
    float* pooled  = wsF + 65536;

    const size_t need = (size_t)(65536 + 64 * NSP) * sizeof(float);
    if (ws_size >= need) {
        k_stage1<<<HB + PB, 256, 0, stream>>>(boxes, N, student, pooled, hmv, partial);
        k_final<<<dim3(NSP / 256, 8), 256, 0, stream>>>(pooled, teacher, conv_w, conv_b,
                                                        hmv, partial, out);
    } else {
        k_stage1<<<HB, 256, 0, stream>>>(boxes, N, student, /*P unused*/ hmv, hmv, partial);
        k_final_fused<<<dim3(NSP / 256, 8), 256, 0, stream>>>(student, teacher, conv_w, conv_b,
                                                              hmv, partial, out);
    }
}

// Round 6
// 207.698 us; speedup vs baseline: 1.3106x; 1.0207x over previous
//
#include <hip/hip_runtime.h>
#include <math.h>

#define EPS32 1.1920928955078125e-07f
#define NSP 32768          // 2*128*128 spatial positions
#define HB 128             // heatmap blocks
#define PB 4096            // pool blocks (64ch * 2d * 128h * 64 float4-pairs / 256 thr)

// Clang native vector types — required for __builtin_nontemporal_* (HIP_vector_type structs are rejected)
typedef float v4f __attribute__((ext_vector_type(4)));
typedef float v2f __attribute__((ext_vector_type(2)));

// ---------------- ws layout (float units) ----------------
// 0     : partial[128]
// 1024  : hmv[32768]
// 65536 : pooled[64*32768]

__device__ __forceinline__ float gauss_radius(float h, float w) {
#pragma clang fp contract(off)
    const float mo = 0.1f;
    float b1 = h + w;
    float c1 = w * h * (1.0f - mo) / (1.0f + mo);
    float r1 = (b1 + sqrtf(fmaxf(b1 * b1 - 4.0f * c1, 0.0f))) / 2.0f;
    float b2 = 2.0f * (h + w);
    float c2 = (1.0f - mo) * w * h;
    float r2 = (b2 + sqrtf(fmaxf(b2 * b2 - 16.0f * c2, 0.0f))) / 2.0f;
    float b3 = -2.0f * mo * (h + w);
    float c3 = (mo - 1.0f) * w * h;
    float r3 = (b3 + sqrtf(fmaxf(b3 * b3 - 16.0f * mo * c3, 0.0f))) / 2.0f;
    return fminf(fminf(r1, r2), r3);
}

// blocks [0,HB): heatmap (+ in-LDS box params + per-block partial sum)
// blocks [HB, HB+PB): 2x2x2 average pool of student with nontemporal float4 loads
__global__ void k_stage1(const float* __restrict__ boxes, int N,
                         const float* __restrict__ S,
                         float* __restrict__ P,
                         float* __restrict__ hmv,
                         float* __restrict__ partial) {
    int bx = blockIdx.x;
    int tid = threadIdx.x;

    if (bx < HB) {
        __shared__ int   s_cxi[128], s_cyi[128], s_czi[128], s_rx[128], s_rz[128];
        __shared__ float s_ix[128], s_iz[128];
        if (tid < N) {
#pragma clang fp contract(off)
            int b = tid;
            float x = boxes[b * 9 + 0];
            float y = boxes[b * 9 + 1];
            float z = boxes[b * 9 + 2];
            float wf = boxes[b * 9 + 3] / 0.1f / 8.0f;
            float lf = boxes[b * 9 + 4] / 0.1f / 8.0f;
            float hf = boxes[b * 9 + 5] / 0.2f / 8.0f;
            float r_xy = gauss_radius(lf, wf);
            float r_z  = fmaxf(gauss_radius(lf, hf), gauss_radius(wf, hf));
            int rx = max(2, (int)truncf(r_xy / 0.4f));
            int rz = max(2, (int)truncf(r_z / 1.0f));
            float cx = (x + 51.2f) / 0.4f;
            float cy = (y + 51.2f) / 0.4f;
            float cz = (z + 5.0f) / 1.0f;
            int cxi = (int)cx, cyi = (int)cy, czi = (int)cz;
            int valid = (wf > 0.0f) && (lf > 0.0f) &&
                        cxi >= 0 && cxi < 128 && cyi >= 0 && cyi < 128 &&
                        czi >= 0 && czi <= 1;
            float sx = (2.0f * (float)rx + 1.0f) / 6.0f;
            float sz = (2.0f * (float)rz + 1.0f) / 6.0f;
            s_cxi[b] = cxi;
            s_cyi[b] = cyi;
            s_czi[b] = czi;
            s_rx[b]  = valid ? rx : -1;   // rx=-1 makes window test always fail
            s_rz[b]  = rz;
            s_ix[b]  = 1.0f / (2.0f * sx * sx);
            s_iz[b]  = 1.0f / (2.0f * sz * sz);
        }
        __syncthreads();

        int i = bx * 256 + tid;
        int y = i & 127, x = (i >> 7) & 127, zc = i >> 14;
        float m = 0.0f;
        for (int b = 0; b < N; ++b) {
            int rx = s_rx[b];
            int dx = x - s_cxi[b];
            if (dx > rx || dx < -rx) continue;
            int dy = y - s_cyi[b];
            if (dy > rx || dy < -rx) continue;
            int rz = s_rz[b];
            int dz = zc - s_czi[b];
            if (dz > rz || dz < -rz) continue;
            float e = (float)(dx * dx + dy * dy) * s_ix[b]
                    + (float)(dz * dz) * s_iz[b];
            float g = expf(-e);
            if (g >= EPS32) m = fmaxf(m, g);
        }
        hmv[i] = m;
        __shared__ float sm[256];
        sm[tid] = m;
        __syncthreads();
        for (int s = 128; s > 0; s >>= 1) {
            if (tid < s) sm[tid] += sm[tid + s];
            __syncthreads();
        }
        if (tid == 0) partial[bx] = sm[0];
    } else {
        int j = (bx - HB) * 256 + tid;        // < 64*2*128*64 = 1048576
        int wp = j & 63;                       // float4 column (row = 64 float4)
        int h  = (j >> 6) & 127;
        int d  = (j >> 13) & 1;
        int c  = j >> 14;
        int zl = d ? 5 : 1;
        const v4f* S4 = (const v4f*)S;
        long base = ((long)(c * 8 + zl) * 256 + 2 * h) * 64 + wp;
        // student is read exactly once -> nontemporal to keep L2 for pooled
        v4f a = __builtin_nontemporal_load(&S4[base]);
        v4f b = __builtin_nontemporal_load(&S4[base + 64]);
        v4f e = __builtin_nontemporal_load(&S4[base + 16384]);   // next z plane
        v4f f = __builtin_nontemporal_load(&S4[base + 16384 + 64]);
        v2f r;
        r.x = (((a.x + a.y) + (b.x + b.y)) + ((e.x + e.y) + (f.x + f.y))) * 0.125f;
        r.y = (((a.z + a.w) + (b.z + b.w)) + ((e.z + e.w) + (f.z + f.w))) * 0.125f;
        ((v2f*)P)[j] = r;
    }
}

// out[o,s] = |dot(W[o,:], P[:,s]) + B[o] - T[o,s]| * hmv[s] * 10/(sum+1e-4)
//
// s-VECTORIZED (float2/thread) + c-outer/o-inner:
//  - each scalar W value feeds 32 FMAs (R4: 16) -> halves scalar-load issue ratio
//  - pooled loads are 512 B/wave, 8 in flight (unroll 8) -> 4 KB/wave MLP
//  - grid 64x8=512 blocks, 2 waves/SIMD; live set acc[16]x2 + 8 pc ~= 70 VGPR
__global__ __launch_bounds__(256, 4)
void k_final(const float* __restrict__ P, const float* __restrict__ T,
             const float* __restrict__ W, const float* __restrict__ Bb,
             const float* __restrict__ hmv, const float* __restrict__ partial,
             float* __restrict__ out) {
    __shared__ float s_scale;
    int tid = threadIdx.x;
    if (tid < 64) {
        float v = partial[tid] + partial[tid + 64];
        for (int off = 32; off > 0; off >>= 1) v += __shfl_down(v, off, 64);
        if (tid == 0) s_scale = 10.0f / (v + 1e-4f);
    }
    __syncthreads();

    int sp = blockIdx.x * 256 + tid;       // float2 index into the s dimension
    int o0 = blockIdx.y * 16;

    v2f acc[16];
#pragma unroll
    for (int oo = 0; oo < 16; ++oo) {
        float b = Bb[o0 + oo];
        acc[oo].x = b; acc[oo].y = b;
    }

    const v2f* Pv = (const v2f*)P;
    const float* Wv = W + o0 * 64;         // wave-uniform -> scalar k-cache loads
#pragma unroll 8
    for (int c = 0; c < 64; ++c) {
        v2f pc = Pv[(long)c * (NSP / 2) + sp];
#pragma unroll
        for (int oo = 0; oo < 16; ++oo) {
            float w = Wv[oo * 64 + c];
            acc[oo].x = fmaf(w, pc.x, acc[oo].x);
            acc[oo].y = fmaf(w, pc.y, acc[oo].y);
        }
    }

    v2f hm2 = ((const v2f*)hmv)[sp];
    float hwx = hm2.x * s_scale, hwy = hm2.y * s_scale;
    const v2f* T2 = (const v2f*)T;
    v2f* O2 = (v2f*)out;
#pragma unroll
    for (int oo = 0; oo < 16; ++oo) {
        long idx = (long)(o0 + oo) * (NSP / 2) + sp;
        v2f tv = __builtin_nontemporal_load(&T2[idx]);   // teacher read-once
        v2f r;
        r.x = fabsf(acc[oo].x - tv.x) * hwx;
        r.y = fabsf(acc[oo].y - tv.y) * hwy;
        __builtin_nontemporal_store(r, &O2[idx]);        // out write-once
    }
}

// Fallback (ws too small for pooled buffer): pool inline, c-outer as well.
__global__ __launch_bounds__(256, 2)
void k_final_fused(const float* __restrict__ S, const float* __restrict__ T,
                   const float* __restrict__ W, const float* __restrict__ Bb,
                   const float* __restrict__ hmv, const float* __restrict__ partial,
                   float* __restrict__ out) {
    __shared__ float s_scale;
    int tid = threadIdx.x;
    if (tid < 64) {
        float v = partial[tid] + partial[tid + 64];
        for (int off = 32; off > 0; off >>= 1) v += __shfl_down(v, off, 64);
        if (tid == 0) s_scale = 10.0f / (v + 1e-4f);
    }
    __syncthreads();
    int s = blockIdx.x * 256 + tid;
    int w = s & 127, h = (s >> 7) & 127, d = s >> 14;
    int zl = d ? 5 : 1;
    const v2f* S2 = (const v2f*)S;
    int o0 = blockIdx.y * 16;
    float acc[16];
#pragma unroll
    for (int oo = 0; oo < 16; ++oo) acc[oo] = Bb[o0 + oo];
    const float* Wv = W + o0 * 64;
#pragma unroll 4
    for (int c = 0; c < 64; ++c) {
        long base = ((long)(c * 8 + zl) * 256 + 2 * h) * 128 + w;
        v2f a = S2[base];
        v2f b = S2[base + 128];
        v2f e = S2[base + 32768];
        v2f f = S2[base + 32768 + 128];
        float pc = (((a.x + a.y) + (b.x + b.y)) + ((e.x + e.y) + (f.x + f.y))) * 0.125f;
#pragma unroll
        for (int oo = 0; oo < 16; ++oo)
            acc[oo] = fmaf(Wv[oo * 64 + c], pc, acc[oo]);
    }
    float hmw = hmv[s] * s_scale;
#pragma unroll
    for (int oo = 0; oo < 16; ++oo) {
        int o = o0 + oo;
        out[(long)o * NSP + s] = fabsf(acc[oo] - T[(long)o * NSP + s]) * hmw;
    }
}

extern "C" void kernel_launch(void* const* d_in, const int* in_sizes, int n_in,
                              void* d_out, int out_size, void* d_ws, size_t ws_size,
                              hipStream_t stream) {
    const float* boxes   = (const float*)d_in[0];
    // d_in[1] = gt_labels_3d (unused by the reference output)
    const float* teacher = (const float*)d_in[2];
    const float* student = (const float*)d_in[3];
    const float* conv_w  = (const float*)d_in[4];
    const float* conv_b  = (const float*)d_in[5];
    float* out = (float*)d_out;

    int N = in_sizes[0] / 9;
    if (N > 128) N = 128;

    float* wsF     = (float*)d_ws;
    float* partial = wsF;
    float* hmv     = wsF + 1024;
    float* pooled  = wsF + 65536;

    const size_t need = (size_t)(65536 + 64 * NSP) * sizeof(float);
    if (ws_size >= need) {
        k_stage1<<<HB + PB, 256, 0, stream>>>(boxes, N, student, pooled, hmv, partial);
        k_final<<<dim3(NSP / 512, 8), 256, 0, stream>>>(pooled, teacher, conv_w, conv_b,
                                                        hmv, partial, out);
    } else {
        k_stage1<<<HB, 256, 0, stream>>>(boxes, N, student, /*P unused*/ hmv, hmv, partial);
        k_final_fused<<<dim3(NSP / 256, 8), 256, 0, stream>>>(student, teacher, conv_w, conv_b,
                                                              hmv, partial, out);
    }
}

// Round 9
// 206.936 us; speedup vs baseline: 1.3154x; 1.0037x over previous
//
#include <hip/hip_runtime.h>
#include <math.h>

#define EPS32 1.1920928955078125e-07f
#define NSP 32768          // 2*128*128 spatial positions
#define HB 128             // heatmap blocks
#define PB 4096            // pool blocks (64ch * 2d * 128h * 64 float4-pairs / 256 thr)

// Clang native vector types — required for __builtin_nontemporal_* (HIP_vector_type structs are rejected)
typedef float v4f __attribute__((ext_vector_type(4)));
typedef float v2f __attribute__((ext_vector_type(2)));

// ---------------- ws layout (float units) ----------------
// 0     : partial[128]
// 1024  : hmv[32768]
// 65536 : pooled[64*32768]

__device__ __forceinline__ float gauss_radius(float h, float w) {
#pragma clang fp contract(off)
    const float mo = 0.1f;
    float b1 = h + w;
    float c1 = w * h * (1.0f - mo) / (1.0f + mo);
    float r1 = (b1 + sqrtf(fmaxf(b1 * b1 - 4.0f * c1, 0.0f))) / 2.0f;
    float b2 = 2.0f * (h + w);
    float c2 = (1.0f - mo) * w * h;
    float r2 = (b2 + sqrtf(fmaxf(b2 * b2 - 16.0f * c2, 0.0f))) / 2.0f;
    float b3 = -2.0f * mo * (h + w);
    float c3 = (mo - 1.0f) * w * h;
    float r3 = (b3 + sqrtf(fmaxf(b3 * b3 - 16.0f * mo * c3, 0.0f))) / 2.0f;
    return fminf(fminf(r1, r2), r3);
}

// blocks [0,HB): heatmap (+ in-LDS box params + per-block partial sum)
// blocks [HB, HB+PB): 2x2x2 average pool of student with nontemporal float4 loads
__global__ void k_stage1(const float* __restrict__ boxes, int N,
                         const float* __restrict__ S,
                         float* __restrict__ P,
                         float* __restrict__ hmv,
                         float* __restrict__ partial) {
    int bx = blockIdx.x;
    int tid = threadIdx.x;

    if (bx < HB) {
        __shared__ int   s_cxi[128], s_cyi[128], s_czi[128], s_rx[128], s_rz[128];
        __shared__ float s_ix[128], s_iz[128];
        if (tid < N) {
#pragma clang fp contract(off)
            int b = tid;
            float x = boxes[b * 9 + 0];
            float y = boxes[b * 9 + 1];
            float z = boxes[b * 9 + 2];
            float wf = boxes[b * 9 + 3] / 0.1f / 8.0f;
            float lf = boxes[b * 9 + 4] / 0.1f / 8.0f;
            float hf = boxes[b * 9 + 5] / 0.2f / 8.0f;
            float r_xy = gauss_radius(lf, wf);
            float r_z  = fmaxf(gauss_radius(lf, hf), gauss_radius(wf, hf));
            int rx = max(2, (int)truncf(r_xy / 0.4f));
            int rz = max(2, (int)truncf(r_z / 1.0f));
            float cx = (x + 51.2f) / 0.4f;
            float cy = (y + 51.2f) / 0.4f;
            float cz = (z + 5.0f) / 1.0f;
            int cxi = (int)cx, cyi = (int)cy, czi = (int)cz;
            int valid = (wf > 0.0f) && (lf > 0.0f) &&
                        cxi >= 0 && cxi < 128 && cyi >= 0 && cyi < 128 &&
                        czi >= 0 && czi <= 1;
            float sx = (2.0f * (float)rx + 1.0f) / 6.0f;
            float sz = (2.0f * (float)rz + 1.0f) / 6.0f;
            s_cxi[b] = cxi;
            s_cyi[b] = cyi;
            s_czi[b] = czi;
            s_rx[b]  = valid ? rx : -1;   // rx=-1 makes window test always fail
            s_rz[b]  = rz;
            s_ix[b]  = 1.0f / (2.0f * sx * sx);
            s_iz[b]  = 1.0f / (2.0f * sz * sz);
        }
        __syncthreads();

        int i = bx * 256 + tid;
        int y = i & 127, x = (i >> 7) & 127, zc = i >> 14;
        float m = 0.0f;
        for (int b = 0; b < N; ++b) {
            int rx = s_rx[b];
            int dx = x - s_cxi[b];
            if (dx > rx || dx < -rx) continue;
            int dy = y - s_cyi[b];
            if (dy > rx || dy < -rx) continue;
            int rz = s_rz[b];
            int dz = zc - s_czi[b];
            if (dz > rz || dz < -rz) continue;
            float e = (float)(dx * dx + dy * dy) * s_ix[b]
                    + (float)(dz * dz) * s_iz[b];
            float g = expf(-e);
            if (g >= EPS32) m = fmaxf(m, g);
        }
        hmv[i] = m;
        __shared__ float sm[256];
        sm[tid] = m;
        __syncthreads();
        for (int s = 128; s > 0; s >>= 1) {
            if (tid < s) sm[tid] += sm[tid + s];
            __syncthreads();
        }
        if (tid == 0) partial[bx] = sm[0];
    } else {
        int j = (bx - HB) * 256 + tid;        // < 64*2*128*64 = 1048576
        int wp = j & 63;                       // float4 column (row = 64 float4)
        int h  = (j >> 6) & 127;
        int d  = (j >> 13) & 1;
        int c  = j >> 14;
        int zl = d ? 5 : 1;
        const v4f* S4 = (const v4f*)S;
        long base = ((long)(c * 8 + zl) * 256 + 2 * h) * 64 + wp;
        // student is read exactly once -> nontemporal to keep L2 for pooled
        v4f a = __builtin_nontemporal_load(&S4[base]);
        v4f b = __builtin_nontemporal_load(&S4[base + 64]);
        v4f e = __builtin_nontemporal_load(&S4[base + 16384]);   // next z plane
        v4f f = __builtin_nontemporal_load(&S4[base + 16384 + 64]);
        v2f r;
        r.x = (((a.x + a.y) + (b.x + b.y)) + ((e.x + e.y) + (f.x + f.y))) * 0.125f;
        r.y = (((a.z + a.w) + (b.z + b.w)) + ((e.z + e.w) + (f.z + f.w))) * 0.125f;
        ((v2f*)P)[j] = r;
    }
}

// out[o,s] = |dot(W[o,:], P[:,s]) + B[o] - T[o,s]| * hmv[s] * 10/(sum+1e-4)
//
// W-TILE IN LDS (the R6 failure: Wv[oo*64+c] wave-uniform reads compile to
// ~1024 serialized s_load+lgkmcnt per thread at ~100cyc = the ~45us floor
// k_final was stuck at across R3/R4/R6 — scalar-pipe latency bound, which is
// why VALUBusy=12% AND hbm=820GB/s were BOTH low).
// Inner loop: ds_read_b64 broadcast (conflict-free) feeds 4 FMAs — DS and
// VALU pipes balanced. o-group 8, grid 64x16=1024 blocks -> 4 waves/SIMD.
__global__ __launch_bounds__(256, 4)
void k_final(const float* __restrict__ P, const float* __restrict__ T,
             const float* __restrict__ W, const float* __restrict__ Bb,
             const float* __restrict__ hmv, const float* __restrict__ partial,
             float* __restrict__ out) {
    __shared__ float s_scale;
    __shared__ float sW[8 * 64];           // W o-tile, row-major [oo][c], 2 KB
    int tid = threadIdx.x;
    int o0 = blockIdx.y * 8;

    // stage W tile: 512 floats by 256 threads
    sW[tid]       = W[o0 * 64 + tid];
    sW[tid + 256] = W[o0 * 64 + tid + 256];

    if (tid < 64) {
        float v = partial[tid] + partial[tid + 64];
        for (int off = 32; off > 0; off >>= 1) v += __shfl_down(v, off, 64);
        if (tid == 0) s_scale = 10.0f / (v + 1e-4f);
    }
    __syncthreads();

    int sp = blockIdx.x * 256 + tid;       // float2 index into the s dimension

    v2f acc[8];
#pragma unroll
    for (int oo = 0; oo < 8; ++oo) {
        float b = Bb[o0 + oo];
        acc[oo].x = b; acc[oo].y = b;
    }

    const v2f* Pv = (const v2f*)P;
    const v2f* W2 = (const v2f*)sW;        // [oo][c2], 32 v2f per row
#pragma unroll 4
    for (int c2 = 0; c2 < 32; ++c2) {
        v2f pc0 = Pv[(long)(2 * c2)     * (NSP / 2) + sp];
        v2f pc1 = Pv[(long)(2 * c2 + 1) * (NSP / 2) + sp];
#pragma unroll
        for (int oo = 0; oo < 8; ++oo) {
            v2f w = W2[oo * 32 + c2];      // LDS broadcast, ds_read_b64
            acc[oo].x = fmaf(w.x, pc0.x, acc[oo].x);
            acc[oo].y = fmaf(w.x, pc0.y, acc[oo].y);
            acc[oo].x = fmaf(w.y, pc1.x, acc[oo].x);
            acc[oo].y = fmaf(w.y, pc1.y, acc[oo].y);
        }
    }

    v2f hm2 = ((const v2f*)hmv)[sp];
    float hwx = hm2.x * s_scale, hwy = hm2.y * s_scale;
    const v2f* T2 = (const v2f*)T;
    v2f* O2 = (v2f*)out;
#pragma unroll
    for (int oo = 0; oo < 8; ++oo) {
        long idx = (long)(o0 + oo) * (NSP / 2) + sp;
        v2f tv = __builtin_nontemporal_load(&T2[idx]);   // teacher read-once
        v2f r;
        r.x = fabsf(acc[oo].x - tv.x) * hwx;
        r.y = fabsf(acc[oo].y - tv.y) * hwy;
        __builtin_nontemporal_store(r, &O2[idx]);        // out write-once
    }
}

// Fallback (ws too small for pooled buffer): pool inline; W-tile in LDS too.
__global__ __launch_bounds__(256, 2)
void k_final_fused(const float* __restrict__ S, const float* __restrict__ T,
                   const float* __restrict__ W, const float* __restrict__ Bb,
                   const float* __restrict__ hmv, const float* __restrict__ partial,
                   float* __restrict__ out) {
    __shared__ float s_scale;
    __shared__ float sW[16 * 64];
    int tid = threadIdx.x;
    int o0 = blockIdx.y * 16;
#pragma unroll
    for (int k = 0; k < 4; ++k) sW[tid + k * 256] = W[o0 * 64 + tid + k * 256];
    if (tid < 64) {
        float v = partial[tid] + partial[tid + 64];
        for (int off = 32; off > 0; off >>= 1) v += __shfl_down(v, off, 64);
        if (tid == 0) s_scale = 10.0f / (v + 1e-4f);
    }
    __syncthreads();
    int s = blockIdx.x * 256 + tid;
    int w = s & 127, h = (s >> 7) & 127, d = s >> 14;
    int zl = d ? 5 : 1;
    const v2f* S2 = (const v2f*)S;
    float acc[16];
#pragma unroll
    for (int oo = 0; oo < 16; ++oo) acc[oo] = Bb[o0 + oo];
#pragma unroll 4
    for (int c = 0; c < 64; ++c) {
        long base = ((long)(c * 8 + zl) * 256 + 2 * h) * 128 + w;
        v2f a = S2[base];
        v2f b = S2[base + 128];
        v2f e = S2[base + 32768];
        v2f f = S2[base + 32768 + 128];
        float pc = (((a.x + a.y) + (b.x + b.y)) + ((e.x + e.y) + (f.x + f.y))) * 0.125f;
#pragma unroll
        for (int oo = 0; oo < 16; ++oo)
            acc[oo] = fmaf(sW[oo * 64 + c], pc, acc[oo]);
    }
    float hmw = hmv[s] * s_scale;
#pragma unroll
    for (int oo = 0; oo < 16; ++oo) {
        int o = o0 + oo;
        out[(long)o * NSP + s] = fabsf(acc[oo] - T[(long)o * NSP + s]) * hmw;
    }
}

extern "C" void kernel_launch(void* const* d_in, const int* in_sizes, int n_in,
                              void* d_out, int out_size, void* d_ws, size_t ws_size,
                              hipStream_t stream) {
    const float* boxes   = (const float*)d_in[0];
    // d_in[1] = gt_labels_3d (unused by the reference output)
    const float* teacher = (const float*)d_in[2];
    const float* student = (const float*)d_in[3];
    const float* conv_w  = (const float*)d_in[4];
    const float* conv_b  = (const float*)d_in[5];
    float* out = (float*)d_out;

    int N = in_sizes[0] / 9;
    if (N > 128) N = 128;

    float* wsF     = (float*)d_ws;
    float* partial = wsF;
    float* hmv     = wsF + 1024;
    float* pooled  = wsF + 65536;

    const size_t need = (size_t)(65536 + 64 * NSP) * sizeof(float);
    if (ws_size >= need) {
        k_stage1<<<HB + PB, 256, 0, stream>>>(boxes, N, student, pooled, hmv, partial);
        k_final<<<dim3(NSP / 512, 16), 256, 0, stream>>>(pooled, teacher, conv_w, conv_b,
                                                         hmv, partial, out);
    } else {
        k_stage1<<<HB, 256, 0, stream>>>(boxes, N, student, /*P unused*/ hmv, hmv, partial);
        k_final_fused<<<dim3(NSP / 256, 8), 256, 0, stream>>>(student, teacher, conv_w, conv_b,
                                                              hmv, partial, out);
    }
}